// Round 6
// baseline (326.364 us; speedup 1.0000x reference)
//
#include <hip/hip_runtime.h>
#include <hip/hip_bf16.h>

typedef float f32x4 __attribute__((ext_vector_type(4)));
typedef short bf16x8 __attribute__((ext_vector_type(8)));
typedef short bf16x4 __attribute__((ext_vector_type(4)));

static __device__ __forceinline__ short f2bs(float f) {
  __hip_bfloat16 h = __float2bfloat16(f);
  union { __hip_bfloat16 h; short s; } u;
  u.h = h;
  return u.s;
}

// async global->LDS, 16B per lane; LDS dest = wave-uniform base + lane*16
#define GLDS(gp, lp) __builtin_amdgcn_global_load_lds( \
    (const __attribute__((address_space(1))) unsigned int*)(gp), \
    (__attribute__((address_space(3))) unsigned int*)(lp), 16, 0, 0)

// ---------------- elementwise f32 -> bf16 ----------------
__global__ __launch_bounds__(256) void cvt_f32_bf16(const float* __restrict__ in,
                                                    short* __restrict__ out, int n4) {
  int i = blockIdx.x * 256 + threadIdx.x;
  if (i >= n4) return;
  f32x4 v = ((const f32x4*)in)[i];
  bf16x4 o;
  o[0] = f2bs(v[0]); o[1] = f2bs(v[1]); o[2] = f2bs(v[2]); o[3] = f2bs(v[3]);
  ((bf16x4*)out)[i] = o;
}

// ---------------- transpose f32 [R][C] -> bf16 [C][R] ----------------
__global__ __launch_bounds__(256) void transpose_cvt(const float* __restrict__ in,
                                                     short* __restrict__ out,
                                                     int R, int C) {
  __shared__ float tile[32][33];
  int bx = blockIdx.x * 32;  // col base (C dim)
  int by = blockIdx.y * 32;  // row base (R dim)
  int tx = threadIdx.x & 31;
  int ty = threadIdx.x >> 5;
#pragma unroll
  for (int i = 0; i < 32; i += 8)
    tile[ty + i][tx] = in[(long)(by + ty + i) * C + bx + tx];
  __syncthreads();
#pragma unroll
  for (int i = 0; i < 32; i += 8)
    out[(long)(bx + ty + i) * R + by + tx] = f2bs(tile[tx][ty + i]);
}

// ------- GEMM main loop: A via double-buffered LDS, B direct from global ----
// C[128x128] += A[M,K] @ Bt[N,K]^T.
// LDS-BW relief: only A is staged (2 GLDS/wave/iter, 4 ds_read_b128/wave/iter);
// B fragments stream from global (L2-resident weights) on the parallel vector-
// memory path, register-prefetched one K-iter ahead (drained at the next
// barrier, one full compute phase after issue).
__device__ __forceinline__ void gemm_compute_tile(const short* Ac, const bf16x8 bfr[4],
                                                  int r0, int lr, int quad,
                                                  f32x4 acc[4][4]) {
  bf16x8 af[4];
#pragma unroll
  for (int i = 0; i < 4; ++i)
    af[i] = *(const bf16x8*)(Ac + (r0 + i * 16 + lr) * 32 + quad * 8);
#pragma unroll
  for (int i = 0; i < 4; ++i)
#pragma unroll
    for (int j = 0; j < 4; ++j)
      acc[i][j] = __builtin_amdgcn_mfma_f32_16x16x32_bf16(af[i], bfr[j], acc[i][j], 0, 0, 0);
}

__device__ __forceinline__ void gemm_mainloop(const short* __restrict__ A,
                                              const short* __restrict__ Bt,
                                              int K, int rowA0, int rowB0,
                                              short* As,  // 2 * 128*32 shorts
                                              f32x4 acc[4][4]) {
  const int tid = threadIdx.x;
  const int wave = tid >> 6;
  const int lane = tid & 63;
  const int lr = lane & 15;
  const int quad = lane >> 4;
  const short* aP = A + (long)(rowA0 + wave * 32 + (lane >> 2)) * K + (lane & 3) * 8;
  short* aL0 = As + wave * 32 * 32;
  short* aL1 = As + 128 * 32 + wave * 32 * 32;
  const int r0 = (wave >> 1) * 64;
  const int c16K = 16 * K;
  // B fragment base: col = rowB0 + (wave&1)*64 + j*16 + lr, 16B at k0+quad*8
  const short* bBase = Bt + (long)(rowB0 + (wave & 1) * 64 + lr) * K + quad * 8;
  // prologue: A tile0 -> buf0; B frags for k0=0
  GLDS(aP, aL0);
  GLDS(aP + c16K, aL0 + 16 * 32);
  aP += 32;
  bf16x8 bc[4], bn[4];
#pragma unroll
  for (int j = 0; j < 4; ++j)
    bc[j] = *(const bf16x8*)(bBase + j * c16K);
  const int nIter = K >> 5;   // must be even (K=1024 -> 32)
#pragma unroll 1
  for (int i = 0; i < nIter; i += 2) {
    __syncthreads();                       // A_i (buf0) ready; drains B loads too
    if (i + 1 < nIter) {                   // stage A_{i+1} -> buf1
      GLDS(aP, aL1);
      GLDS(aP + c16K, aL1 + 16 * 32);
      aP += 32;
    }
    {
      int k1 = (i + 1 < nIter) ? (i + 1) * 32 : 0;   // clamp avoids OOB
#pragma unroll
      for (int j = 0; j < 4; ++j)
        bn[j] = *(const bf16x8*)(bBase + j * c16K + k1);
    }
    gemm_compute_tile(As + wave * 0 + 0 * 0 + 0, bc, r0, lr, quad, acc);  // buf0
    __syncthreads();                       // A_{i+1} (buf1) ready
    if (i + 2 < nIter) {                   // stage A_{i+2} -> buf0
      GLDS(aP, aL0);
      GLDS(aP + c16K, aL0 + 16 * 32);
      aP += 32;
    }
    {
      int k2 = (i + 2 < nIter) ? (i + 2) * 32 : 0;
#pragma unroll
      for (int j = 0; j < 4; ++j)
        bc[j] = *(const bf16x8*)(bBase + j * c16K + k2);
    }
    gemm_compute_tile(As + 128 * 32, bn, r0, lr, quad, acc);              // buf1
  }
}

// ---------------- GEMM1: qkv = x @ w_qkv, scatter into q/k/v^T ----------------
__global__ __launch_bounds__(256, 3) void gemm_qkv(const short* __restrict__ xb,
                                                   const short* __restrict__ wT,
                                                   short* __restrict__ q,
                                                   short* __restrict__ k,
                                                   short* __restrict__ vt) {
  __shared__ __align__(16) short As[2 * 128 * 32];
  f32x4 acc[4][4];
#pragma unroll
  for (int i = 0; i < 4; ++i)
#pragma unroll
    for (int j = 0; j < 4; ++j)
      acc[i][j] = (f32x4){0.f, 0.f, 0.f, 0.f};
  const int tileM = blockIdx.x * 128;
  const int tileN = blockIdx.y * 128;
  gemm_mainloop(xb, wT, 1024, tileM, tileN, As, acc);
  const int tid = threadIdx.x;
  const int wave = tid >> 6;
  const int lane = tid & 63;
  const int lr = lane & 15;
  const int quad = lane >> 4;
#pragma unroll
  for (int i = 0; i < 4; ++i) {
    const int row0 = tileM + (wave >> 1) * 64 + i * 16 + quad * 4;  // 4 consecutive rows
    const int b = row0 >> 11;
    const int t = row0 & 2047;
#pragma unroll
    for (int j = 0; j < 4; ++j) {
      int col = tileN + (wave & 1) * 64 + j * 16 + lr;
      int region = col >> 10;    // 0=q 1=k 2=v (wave-uniform: region boundary % 16 == 0)
      int w = col & 1023;
      int h = w >> 6;
      int d = w & 63;
      long bh = (long)b * 16 + h;
      if (region == 0) {
#pragma unroll
        for (int r = 0; r < 4; ++r)
          q[(bh * 2048 + t + r) * 64 + d] = f2bs(acc[i][j][r] * 0.03125f);  // fold 1/sqrt(C)
      } else if (region == 1) {
#pragma unroll
        for (int r = 0; r < 4; ++r)
          k[(bh * 2048 + t + r) * 64 + d] = f2bs(acc[i][j][r]);
      } else {
        bf16x4 pk;  // 4 consecutive t -> one b64 store into vt[bh][d][t..t+3]
#pragma unroll
        for (int r = 0; r < 4; ++r) pk[r] = f2bs(acc[i][j][r]);
        *(bf16x4*)(vt + (bh * 64 + d) * 2048 + t) = pk;
      }
    }
  }
}

// ---------------- flash attention with ALiBi + causal ----------------
// 2048 blocks, one 64-row q-tile each, dispatched in descending-j order
// (LPT schedule). Fixed-max softmax (max=2.0): no online max/rescale; l is a
// plain sum reduced at the epilogue. S^T orientation -> b64 packed P commits.
// Bias held in 16 registers incremented per k-tile; diagonal causal mask
// precomputed as an integer bitmask.
__global__ __launch_bounds__(256, 5) void attn(const short* __restrict__ q,
                                               const short* __restrict__ kk,
                                               const short* __restrict__ vt,
                                               short* __restrict__ cat) {
  __shared__ __align__(16) short Ks[64 * 72];       // [kpos][dh], pad 72
  __shared__ __align__(16) short Vs[64 * 72];       // [d][kpos], pad 72
  __shared__ __align__(16) short Ps[4 * 16 * 72];   // per-wave P [m=16][k=64+pad]
  const int bx = blockIdx.x;                        // 0..2047
  const int j = 31 - (bx >> 6);                     // q-tile index (64 rows)
  const int bh = bx & 63;
  const int h = bh & 15;
  const int b = bh >> 4;
  const int tid = threadIdx.x;
  const int wave = tid >> 6;
  const int lane = tid & 63;
  const int lr = lane & 15;
  const int quad = lane >> 4;
  const float l2e = 1.44269504f;
  const float slope = exp2f(-0.5f * (float)(h + 1));   // 2^(-(h+1)/2)
  const float slope_l2e = slope * l2e;
  const float c2 = -2.0f * l2e;                        // fixed max = 2.0
  const int d_cut = (int)ceilf(20.0f * exp2f(0.5f * (float)(h + 1)));
  const short* kbg = kk + (long)bh * 2048 * 64;
  const short* vbg = vt + (long)bh * 64 * 2048;
  const int srow = tid >> 3;          // 0..31
  const int scol = (tid & 7) * 8;     // 0..56
  short* pw = Ps + wave * 16 * 72;

  const int q0 = j * 64;
  const int mrow0 = q0 + wave * 16;           // this wave's 16 q-rows (m = lr)
  const int kt_start = max(0, (q0 - d_cut) >> 6);
  const short* qptr = q + ((long)bh * 2048 + mrow0) * 64;
  bf16x8 qf0 = *(const bf16x8*)(qptr + (long)lr * 64 + quad * 8);
  bf16x8 qf1 = *(const bf16x8*)(qptr + (long)lr * 64 + 32 + quad * 8);
  float lp = 0.f;                             // per-lane partial row-sum (m=lr)
  f32x4 O[4];
#pragma unroll
  for (int dt = 0; dt < 4; ++dt) O[dt] = (f32x4){0.f, 0.f, 0.f, 0.f};
  // bias regs: bias[ct][r] = slope_l2e*(kbase + ct*16+quad*4+r - mrow0 - lr) + c2
  float bias[4][4];
  unsigned okbits = 0;                        // diag-tile causal mask (dist<=0)
#pragma unroll
  for (int ct = 0; ct < 4; ++ct)
#pragma unroll
    for (int r = 0; r < 4; ++r) {
      int off = ct * 16 + quad * 4 + r;
      bias[ct][r] = slope_l2e * (float)(kt_start * 64 + off - mrow0 - lr) + c2;
      if (off - wave * 16 - lr <= 0) okbits |= 1u << (ct * 4 + r);
    }
  const float bstep = slope_l2e * 64.0f;

  // prefetch first tile into registers
  const short* kg = kbg + (long)kt_start * 64 * 64;
  const short* vg = vbg + kt_start * 64;
  bf16x8 pk0 = *(const bf16x8*)(kg + srow * 64 + scol);
  bf16x8 pk1 = *(const bf16x8*)(kg + (srow + 32) * 64 + scol);
  bf16x8 pv0 = *(const bf16x8*)(vg + (long)srow * 2048 + scol);
  bf16x8 pv1 = *(const bf16x8*)(vg + (long)(srow + 32) * 2048 + scol);
  for (int kt = kt_start; kt <= j; ++kt) {
    *(bf16x8*)(Ks + srow * 72 + scol) = pk0;
    *(bf16x8*)(Ks + (srow + 32) * 72 + scol) = pk1;
    *(bf16x8*)(Vs + srow * 72 + scol) = pv0;
    *(bf16x8*)(Vs + (srow + 32) * 72 + scol) = pv1;
    __syncthreads();  // LDS tile ready
    if (kt < j) {     // issue next tile's loads; latency overlaps compute
      const short* kg2 = kbg + (long)(kt + 1) * 64 * 64;
      const short* vg2 = vbg + (kt + 1) * 64;
      pk0 = *(const bf16x8*)(kg2 + srow * 64 + scol);
      pk1 = *(const bf16x8*)(kg2 + (srow + 32) * 64 + scol);
      pv0 = *(const bf16x8*)(vg2 + (long)srow * 2048 + scol);
      pv1 = *(const bf16x8*)(vg2 + (long)(srow + 32) * 2048 + scol);
    }
    // S^T = K Q^T: lane holds S^T[k = kbase+ct*16+quad*4+r][m = mrow0+lr]
    f32x4 S[4];
#pragma unroll
    for (int ct = 0; ct < 4; ++ct) {
      bf16x8 kf0 = *(const bf16x8*)(Ks + (ct * 16 + lr) * 72 + quad * 8);
      bf16x8 kf1 = *(const bf16x8*)(Ks + (ct * 16 + lr) * 72 + 32 + quad * 8);
      f32x4 a = (f32x4){0.f, 0.f, 0.f, 0.f};
      a = __builtin_amdgcn_mfma_f32_16x16x32_bf16(kf0, qf0, a, 0, 0, 0);
      a = __builtin_amdgcn_mfma_f32_16x16x32_bf16(kf1, qf1, a, 0, 0, 0);
      S[ct] = a;
    }
    // fixed-max softmax: p = exp2(S*l2e + bias)
    const bool diag = (kt == j);
#pragma unroll
    for (int ct = 0; ct < 4; ++ct) {
      bf16x4 pkt;
#pragma unroll
      for (int r = 0; r < 4; ++r) {
        float arg = fmaf(S[ct][r], l2e, bias[ct][r]);
        if (diag && !(okbits & (1u << (ct * 4 + r)))) arg = -10000.0f;  // causal
        float p = exp2f(arg);
        lp += p;
        pkt[r] = f2bs(p);
        bias[ct][r] += bstep;
      }
      // 4 consecutive k -> one b64 write into P[m=lr][k]
      *(bf16x4*)(pw + lr * 72 + ct * 16 + quad * 4) = pkt;
    }
    asm volatile("s_waitcnt lgkmcnt(0)" ::: "memory");  // wave-private scratch
    bf16x8 pf0 = *(const bf16x8*)(pw + lr * 72 + quad * 8);
    bf16x8 pf1 = *(const bf16x8*)(pw + lr * 72 + 32 + quad * 8);
#pragma unroll
    for (int dt = 0; dt < 4; ++dt) {
      bf16x8 vf0 = *(const bf16x8*)(Vs + (dt * 16 + lr) * 72 + quad * 8);
      bf16x8 vf1 = *(const bf16x8*)(Vs + (dt * 16 + lr) * 72 + 32 + quad * 8);
      O[dt] = __builtin_amdgcn_mfma_f32_16x16x32_bf16(pf0, vf0, O[dt], 0, 0, 0);
      O[dt] = __builtin_amdgcn_mfma_f32_16x16x32_bf16(pf1, vf1, O[dt], 0, 0, 0);
    }
    __syncthreads();  // all waves done with Ks/Vs before next commit
  }
  // reduce l across the 4 quads (lane's partial covers k = {ct*16+quad*4+r})
  lp += __shfl_xor(lp, 16);
  lp += __shfl_xor(lp, 32);   // now every lane holds full l for row m = lr
  // epilogue: O rows are m = quad*4+r -> fetch l via shuffle
#pragma unroll
  for (int r = 0; r < 4; ++r) {
    float lm = __shfl(lp, quad * 4 + r);
    float inv = 1.0f / lm;
    int t = mrow0 + quad * 4 + r;
#pragma unroll
    for (int dt = 0; dt < 4; ++dt)
      cat[((long)b * 2048 + t) * 1024 + h * 64 + dt * 16 + lr] =
          f2bs(O[dt][r] * inv);
  }
}

// ---------------- GEMM2: out = concat @ w_o (fp32 out) ----------------
__global__ __launch_bounds__(256, 3) void gemm_out(const short* __restrict__ cat,
                                                   const short* __restrict__ woT,
                                                   float* __restrict__ out) {
  __shared__ __align__(16) short As[2 * 128 * 32];
  f32x4 acc[4][4];
#pragma unroll
  for (int i = 0; i < 4; ++i)
#pragma unroll
    for (int j = 0; j < 4; ++j)
      acc[i][j] = (f32x4){0.f, 0.f, 0.f, 0.f};
  const int tileM = blockIdx.x * 128;
  const int tileN = blockIdx.y * 128;
  gemm_mainloop(cat, woT, 1024, tileM, tileN, As, acc);
  const int tid = threadIdx.x;
  const int wave = tid >> 6;
  const int lane = tid & 63;
  const int lr = lane & 15;
  const int quad = lane >> 4;
#pragma unroll
  for (int i = 0; i < 4; ++i)
#pragma unroll
    for (int j = 0; j < 4; ++j) {
      int col = tileN + (wave & 1) * 64 + j * 16 + lr;
#pragma unroll
      for (int r = 0; r < 4; ++r) {
        int row = tileM + (wave >> 1) * 64 + i * 16 + quad * 4 + r;
        out[(long)row * 1024 + col] = acc[i][j][r];
      }
    }
}

extern "C" void kernel_launch(void* const* d_in, const int* in_sizes, int n_in,
                              void* d_out, int out_size, void* d_ws, size_t ws_size,
                              hipStream_t stream) {
  const float* x = (const float*)d_in[0];       // [4,2048,1024]
  const float* w_qkv = (const float*)d_in[1];   // [1024,3072]
  const float* w_o = (const float*)d_in[2];     // [1024,1024]
  float* out = (float*)d_out;                   // [4,2048,1024]
  short* ws = (short*)d_ws;
  short* xb = ws;                       // bf16 x; later reused as concat
  short* wqkvT = xb + 8388608;          // [3072][1024]
  short* woT = wqkvT + 3145728;         // [1024][1024]
  short* q = woT + 1048576;             // [B,H,T,dh], pre-scaled 1/32
  short* kb = q + 8388608;              // [B,H,T,dh]
  short* vt = kb + 8388608;             // [B,H,dh,T]

  cvt_f32_bf16<<<8192, 256, 0, stream>>>(x, xb, 2097152);
  transpose_cvt<<<dim3(96, 32), 256, 0, stream>>>(w_qkv, wqkvT, 1024, 3072);
  transpose_cvt<<<dim3(32, 32), 256, 0, stream>>>(w_o, woT, 1024, 1024);
  gemm_qkv<<<dim3(64, 24), 256, 0, stream>>>(xb, wqkvT, q, kb, vt);
  attn<<<dim3(2048), 256, 0, stream>>>(q, kb, vt, xb /*concat reuses xb*/);
  gemm_out<<<dim3(64, 8), 256, 0, stream>>>(xb, woT, out);
}

// Round 7
// 262.949 us; speedup vs baseline: 1.2412x; 1.2412x over previous
//
#include <hip/hip_runtime.h>
#include <hip/hip_bf16.h>

typedef float f32x4 __attribute__((ext_vector_type(4)));
typedef short bf16x8 __attribute__((ext_vector_type(8)));
typedef short bf16x4 __attribute__((ext_vector_type(4)));

static __device__ __forceinline__ short f2bs(float f) {
  __hip_bfloat16 h = __float2bfloat16(f);
  union { __hip_bfloat16 h; short s; } u;
  u.h = h;
  return u.s;
}

// async global->LDS, 16B per lane; LDS dest = wave-uniform base + lane*16
#define GLDS(gp, lp) __builtin_amdgcn_global_load_lds( \
    (const __attribute__((address_space(1))) unsigned int*)(gp), \
    (__attribute__((address_space(3))) unsigned int*)(lp), 16, 0, 0)

// ---------------- elementwise f32 -> bf16 ----------------
__global__ __launch_bounds__(256) void cvt_f32_bf16(const float* __restrict__ in,
                                                    short* __restrict__ out, int n4) {
  int i = blockIdx.x * 256 + threadIdx.x;
  if (i >= n4) return;
  f32x4 v = ((const f32x4*)in)[i];
  bf16x4 o;
  o[0] = f2bs(v[0]); o[1] = f2bs(v[1]); o[2] = f2bs(v[2]); o[3] = f2bs(v[3]);
  ((bf16x4*)out)[i] = o;
}

// ---------------- transpose f32 [R][C] -> bf16 [C][R] ----------------
__global__ __launch_bounds__(256) void transpose_cvt(const float* __restrict__ in,
                                                     short* __restrict__ out,
                                                     int R, int C) {
  __shared__ float tile[32][33];
  int bx = blockIdx.x * 32;  // col base (C dim)
  int by = blockIdx.y * 32;  // row base (R dim)
  int tx = threadIdx.x & 31;
  int ty = threadIdx.x >> 5;
#pragma unroll
  for (int i = 0; i < 32; i += 8)
    tile[ty + i][tx] = in[(long)(by + ty + i) * C + bx + tx];
  __syncthreads();
#pragma unroll
  for (int i = 0; i < 32; i += 8)
    out[(long)(bx + ty + i) * R + by + tx] = f2bs(tile[tx][ty + i]);
}

// ======== round-5 proven structure: A+B staged via GLDS, double-buffered,
// one barrier per K-tile (prefetch next buffer right after barrier). ========
__device__ __forceinline__ void gemm_compute_tile(const short* Ac, const short* Bc,
                                                  int r0, int c0, int lr, int quad,
                                                  f32x4 acc[4][4]) {
  bf16x8 af[4], bfr[4];
#pragma unroll
  for (int i = 0; i < 4; ++i)
    af[i] = *(const bf16x8*)(Ac + (r0 + i * 16 + lr) * 32 + quad * 8);
#pragma unroll
  for (int j = 0; j < 4; ++j)
    bfr[j] = *(const bf16x8*)(Bc + (c0 + j * 16 + lr) * 32 + quad * 8);
#pragma unroll
  for (int i = 0; i < 4; ++i)
#pragma unroll
    for (int j = 0; j < 4; ++j)
      acc[i][j] = __builtin_amdgcn_mfma_f32_16x16x32_bf16(af[i], bfr[j], acc[i][j], 0, 0, 0);
}

// 256-thread / 128x128-tile mainloop (for gemm_out)
__device__ __forceinline__ void gemm_mainloop(const short* __restrict__ A,
                                              const short* __restrict__ Bt,
                                              int K, int rowA0, int rowB0,
                                              short* As, short* Bs,  // each 2*128*32
                                              f32x4 acc[4][4]) {
  const int tid = threadIdx.x;
  const int wave = tid >> 6;
  const int lane = tid & 63;
  const int lr = lane & 15;
  const int quad = lane >> 4;
  const short* aP = A + (long)(rowA0 + wave * 32 + (lane >> 2)) * K + (lane & 3) * 8;
  const short* bP = Bt + (long)(rowB0 + wave * 32 + (lane >> 2)) * K + (lane & 3) * 8;
  const int woff = wave * 32 * 32;
  const int r0 = (wave >> 1) * 64;
  const int c0 = (wave & 1) * 64;
  const int c16K = 16 * K;
  const int BUF = 128 * 32;
  GLDS(aP, As + woff);
  GLDS(aP + c16K, As + woff + 16 * 32);
  GLDS(bP, Bs + woff);
  GLDS(bP + c16K, Bs + woff + 16 * 32);
  aP += 32; bP += 32;
  const int nIter = K >> 5;   // even
#pragma unroll 1
  for (int i = 0; i < nIter; i += 2) {
    __syncthreads();                       // buf0 ready
    if (i + 1 < nIter) {
      GLDS(aP, As + BUF + woff);
      GLDS(aP + c16K, As + BUF + woff + 16 * 32);
      GLDS(bP, Bs + BUF + woff);
      GLDS(bP + c16K, Bs + BUF + woff + 16 * 32);
      aP += 32; bP += 32;
    }
    gemm_compute_tile(As, Bs, r0, c0, lr, quad, acc);
    __syncthreads();                       // buf1 ready
    if (i + 2 < nIter) {
      GLDS(aP, As + woff);
      GLDS(aP + c16K, As + woff + 16 * 32);
      GLDS(bP, Bs + woff);
      GLDS(bP + c16K, Bs + woff + 16 * 32);
      aP += 32; bP += 32;
    }
    gemm_compute_tile(As + BUF, Bs + BUF, r0, c0, lr, quad, acc);
  }
}

// ---------------- GEMM1: qkv = x @ w_qkv, 512 threads, 256x128 tile ----------
// 8 waves in a 4x2 grid (each 64x64). A staged once per 2 wave-columns ->
// fewer staging bytes per MFMA; 48 KB LDS -> 2-3 blocks/CU = 16-24 waves/CU.
__global__ __launch_bounds__(512, 4) void gemm_qkv(const short* __restrict__ xb,
                                                   const short* __restrict__ wT,
                                                   short* __restrict__ q,
                                                   short* __restrict__ k,
                                                   short* __restrict__ vt) {
  __shared__ __align__(16) short As[2 * 256 * 32];   // 32 KB
  __shared__ __align__(16) short Bs[2 * 128 * 32];   // 16 KB
  f32x4 acc[4][4];
#pragma unroll
  for (int i = 0; i < 4; ++i)
#pragma unroll
    for (int j = 0; j < 4; ++j)
      acc[i][j] = (f32x4){0.f, 0.f, 0.f, 0.f};
  const int tileM = blockIdx.x * 256;
  const int tileN = blockIdx.y * 128;
  const int K = 1024;
  const int tid = threadIdx.x;
  const int wave = tid >> 6;       // 0..7
  const int lane = tid & 63;
  const int lr = lane & 15;
  const int quad = lane >> 4;
  const int wrow = wave >> 1;      // 0..3
  const int wcol = wave & 1;       // 0..1
  // staging: wave w covers 16 rows (w*16..w*16+15) per GLDS; lane i -> row i/4, col (i&3)*8
  const short* aP1 = xb + (long)(tileM + wave * 16 + (lane >> 2)) * K + (lane & 3) * 8;
  const short* aP2 = aP1 + (long)128 * K;
  const short* bP  = wT + (long)(tileN + wave * 16 + (lane >> 2)) * K + (lane & 3) * 8;
  const int woff = wave * 16 * 32;
  const int ABUF = 256 * 32, BBUF = 128 * 32;
  const int r0 = wrow * 64;
  const int c0 = wcol * 64;
  GLDS(aP1, As + woff);
  GLDS(aP2, As + 128 * 32 + woff);
  GLDS(bP, Bs + woff);
  aP1 += 32; aP2 += 32; bP += 32;
  const int nIter = K >> 5;   // 32
#pragma unroll 1
  for (int i = 0; i < nIter; i += 2) {
    __syncthreads();                       // buf0 ready
    if (i + 1 < nIter) {
      GLDS(aP1, As + ABUF + woff);
      GLDS(aP2, As + ABUF + 128 * 32 + woff);
      GLDS(bP, Bs + BBUF + woff);
      aP1 += 32; aP2 += 32; bP += 32;
    }
    gemm_compute_tile(As, Bs, r0, c0, lr, quad, acc);
    __syncthreads();                       // buf1 ready
    if (i + 2 < nIter) {
      GLDS(aP1, As + woff);
      GLDS(aP2, As + 128 * 32 + woff);
      GLDS(bP, Bs + woff);
      aP1 += 32; aP2 += 32; bP += 32;
    }
    gemm_compute_tile(As + ABUF, Bs + BBUF, r0, c0, lr, quad, acc);
  }
  // epilogue: scatter into q/k/v^T
#pragma unroll
  for (int i = 0; i < 4; ++i) {
    const int row0 = tileM + wrow * 64 + i * 16 + quad * 4;  // 4 consecutive rows
    const int b = row0 >> 11;
    const int t = row0 & 2047;
#pragma unroll
    for (int j = 0; j < 4; ++j) {
      int col = tileN + wcol * 64 + j * 16 + lr;
      int region = col >> 10;    // 0=q 1=k 2=v (wave-uniform)
      int w = col & 1023;
      int h = w >> 6;
      int d = w & 63;
      long bh = (long)b * 16 + h;
      if (region == 0) {
#pragma unroll
        for (int r = 0; r < 4; ++r)
          q[(bh * 2048 + t + r) * 64 + d] = f2bs(acc[i][j][r] * 0.03125f);  // fold 1/sqrt(C)
      } else if (region == 1) {
#pragma unroll
        for (int r = 0; r < 4; ++r)
          k[(bh * 2048 + t + r) * 64 + d] = f2bs(acc[i][j][r]);
      } else {
        bf16x4 pk;  // 4 consecutive t -> one b64 store into vt[bh][d][t..t+3]
#pragma unroll
        for (int r = 0; r < 4; ++r) pk[r] = f2bs(acc[i][j][r]);
        *(bf16x4*)(vt + (bh * 64 + d) * 2048 + t) = pk;
      }
    }
  }
}

// ---------------- flash attention with ALiBi + causal ----------------
// 2048 blocks, one 64-row q-tile each, descending-j dispatch (LPT schedule).
// Fixed-max softmax (max=2.0): no online max/rescale; l reduced at epilogue.
// S^T orientation -> b64 packed P commits. Bias in registers; causal bitmask.
__global__ __launch_bounds__(256, 5) void attn(const short* __restrict__ q,
                                               const short* __restrict__ kk,
                                               const short* __restrict__ vt,
                                               short* __restrict__ cat) {
  __shared__ __align__(16) short Ks[64 * 72];       // [kpos][dh], pad 72
  __shared__ __align__(16) short Vs[64 * 72];       // [d][kpos], pad 72
  __shared__ __align__(16) short Ps[4 * 16 * 72];   // per-wave P [m=16][k=64+pad]
  const int bx = blockIdx.x;                        // 0..2047
  const int j = 31 - (bx >> 6);                     // q-tile index (64 rows)
  const int bh = bx & 63;
  const int h = bh & 15;
  const int b = bh >> 4;
  const int tid = threadIdx.x;
  const int wave = tid >> 6;
  const int lane = tid & 63;
  const int lr = lane & 15;
  const int quad = lane >> 4;
  const float l2e = 1.44269504f;
  const float slope = exp2f(-0.5f * (float)(h + 1));   // 2^(-(h+1)/2)
  const float slope_l2e = slope * l2e;
  const float c2 = -2.0f * l2e;                        // fixed max = 2.0
  const int d_cut = (int)ceilf(20.0f * exp2f(0.5f * (float)(h + 1)));
  const short* kbg = kk + (long)bh * 2048 * 64;
  const short* vbg = vt + (long)bh * 64 * 2048;
  const int srow = tid >> 3;          // 0..31
  const int scol = (tid & 7) * 8;     // 0..56
  short* pw = Ps + wave * 16 * 72;

  const int q0 = j * 64;
  const int mrow0 = q0 + wave * 16;           // this wave's 16 q-rows (m = lr)
  const int kt_start = max(0, (q0 - d_cut) >> 6);
  const short* qptr = q + ((long)bh * 2048 + mrow0) * 64;
  bf16x8 qf0 = *(const bf16x8*)(qptr + (long)lr * 64 + quad * 8);
  bf16x8 qf1 = *(const bf16x8*)(qptr + (long)lr * 64 + 32 + quad * 8);
  float lp = 0.f;                             // per-lane partial row-sum (m=lr)
  f32x4 O[4];
#pragma unroll
  for (int dt = 0; dt < 4; ++dt) O[dt] = (f32x4){0.f, 0.f, 0.f, 0.f};
  // bias regs: bias[ct][r] = slope_l2e*(kbase + ct*16+quad*4+r - mrow0 - lr) + c2
  float bias[4][4];
  unsigned okbits = 0;                        // diag-tile causal mask (dist<=0)
#pragma unroll
  for (int ct = 0; ct < 4; ++ct)
#pragma unroll
    for (int r = 0; r < 4; ++r) {
      int off = ct * 16 + quad * 4 + r;
      bias[ct][r] = slope_l2e * (float)(kt_start * 64 + off - mrow0 - lr) + c2;
      if (off - wave * 16 - lr <= 0) okbits |= 1u << (ct * 4 + r);
    }
  const float bstep = slope_l2e * 64.0f;

  // prefetch first tile into registers
  const short* kg = kbg + (long)kt_start * 64 * 64;
  const short* vg = vbg + kt_start * 64;
  bf16x8 pk0 = *(const bf16x8*)(kg + srow * 64 + scol);
  bf16x8 pk1 = *(const bf16x8*)(kg + (srow + 32) * 64 + scol);
  bf16x8 pv0 = *(const bf16x8*)(vg + (long)srow * 2048 + scol);
  bf16x8 pv1 = *(const bf16x8*)(vg + (long)(srow + 32) * 2048 + scol);
  for (int kt = kt_start; kt <= j; ++kt) {
    *(bf16x8*)(Ks + srow * 72 + scol) = pk0;
    *(bf16x8*)(Ks + (srow + 32) * 72 + scol) = pk1;
    *(bf16x8*)(Vs + srow * 72 + scol) = pv0;
    *(bf16x8*)(Vs + (srow + 32) * 72 + scol) = pv1;
    __syncthreads();  // LDS tile ready
    if (kt < j) {     // issue next tile's loads; latency overlaps compute
      const short* kg2 = kbg + (long)(kt + 1) * 64 * 64;
      const short* vg2 = vbg + (kt + 1) * 64;
      pk0 = *(const bf16x8*)(kg2 + srow * 64 + scol);
      pk1 = *(const bf16x8*)(kg2 + (srow + 32) * 64 + scol);
      pv0 = *(const bf16x8*)(vg2 + (long)srow * 2048 + scol);
      pv1 = *(const bf16x8*)(vg2 + (long)(srow + 32) * 2048 + scol);
    }
    // S^T = K Q^T: lane holds S^T[k = kbase+ct*16+quad*4+r][m = mrow0+lr]
    f32x4 S[4];
#pragma unroll
    for (int ct = 0; ct < 4; ++ct) {
      bf16x8 kf0 = *(const bf16x8*)(Ks + (ct * 16 + lr) * 72 + quad * 8);
      bf16x8 kf1 = *(const bf16x8*)(Ks + (ct * 16 + lr) * 72 + 32 + quad * 8);
      f32x4 a = (f32x4){0.f, 0.f, 0.f, 0.f};
      a = __builtin_amdgcn_mfma_f32_16x16x32_bf16(kf0, qf0, a, 0, 0, 0);
      a = __builtin_amdgcn_mfma_f32_16x16x32_bf16(kf1, qf1, a, 0, 0, 0);
      S[ct] = a;
    }
    // fixed-max softmax: p = exp2(S*l2e + bias)
    const bool diag = (kt == j);
#pragma unroll
    for (int ct = 0; ct < 4; ++ct) {
      bf16x4 pkt;
#pragma unroll
      for (int r = 0; r < 4; ++r) {
        float arg = fmaf(S[ct][r], l2e, bias[ct][r]);
        if (diag && !(okbits & (1u << (ct * 4 + r)))) arg = -10000.0f;  // causal
        float p = exp2f(arg);
        lp += p;
        pkt[r] = f2bs(p);
        bias[ct][r] += bstep;
      }
      // 4 consecutive k -> one b64 write into P[m=lr][k]
      *(bf16x4*)(pw + lr * 72 + ct * 16 + quad * 4) = pkt;
    }
    asm volatile("s_waitcnt lgkmcnt(0)" ::: "memory");  // wave-private scratch
    bf16x8 pf0 = *(const bf16x8*)(pw + lr * 72 + quad * 8);
    bf16x8 pf1 = *(const bf16x8*)(pw + lr * 72 + 32 + quad * 8);
#pragma unroll
    for (int dt = 0; dt < 4; ++dt) {
      bf16x8 vf0 = *(const bf16x8*)(Vs + (dt * 16 + lr) * 72 + quad * 8);
      bf16x8 vf1 = *(const bf16x8*)(Vs + (dt * 16 + lr) * 72 + 32 + quad * 8);
      O[dt] = __builtin_amdgcn_mfma_f32_16x16x32_bf16(pf0, vf0, O[dt], 0, 0, 0);
      O[dt] = __builtin_amdgcn_mfma_f32_16x16x32_bf16(pf1, vf1, O[dt], 0, 0, 0);
    }
    __syncthreads();  // all waves done with Ks/Vs before next commit
  }
  // reduce l across the 4 quads (lane's partial covers k = {ct*16+quad*4+r})
  lp += __shfl_xor(lp, 16);
  lp += __shfl_xor(lp, 32);   // now every lane holds full l for row m = lr
  // epilogue: O rows are m = quad*4+r -> fetch l via shuffle
#pragma unroll
  for (int r = 0; r < 4; ++r) {
    float lm = __shfl(lp, quad * 4 + r);
    float inv = 1.0f / lm;
    int t = mrow0 + quad * 4 + r;
#pragma unroll
    for (int dt = 0; dt < 4; ++dt)
      cat[((long)b * 2048 + t) * 1024 + h * 64 + dt * 16 + lr] =
          f2bs(O[dt][r] * inv);
  }
}

// ---------------- GEMM2: out = concat @ w_o (fp32 out) ----------------
__global__ __launch_bounds__(256, 5) void gemm_out(const short* __restrict__ cat,
                                                   const short* __restrict__ woT,
                                                   float* __restrict__ out) {
  __shared__ __align__(16) short As[2 * 128 * 32];
  __shared__ __align__(16) short Bs[2 * 128 * 32];
  f32x4 acc[4][4];
#pragma unroll
  for (int i = 0; i < 4; ++i)
#pragma unroll
    for (int j = 0; j < 4; ++j)
      acc[i][j] = (f32x4){0.f, 0.f, 0.f, 0.f};
  const int tileM = blockIdx.x * 128;
  const int tileN = blockIdx.y * 128;
  gemm_mainloop(cat, woT, 1024, tileM, tileN, As, Bs, acc);
  const int tid = threadIdx.x;
  const int wave = tid >> 6;
  const int lane = tid & 63;
  const int lr = lane & 15;
  const int quad = lane >> 4;
#pragma unroll
  for (int i = 0; i < 4; ++i)
#pragma unroll
    for (int j = 0; j < 4; ++j) {
      int col = tileN + (wave & 1) * 64 + j * 16 + lr;
#pragma unroll
      for (int r = 0; r < 4; ++r) {
        int row = tileM + (wave >> 1) * 64 + i * 16 + quad * 4 + r;
        out[(long)row * 1024 + col] = acc[i][j][r];
      }
    }
}

extern "C" void kernel_launch(void* const* d_in, const int* in_sizes, int n_in,
                              void* d_out, int out_size, void* d_ws, size_t ws_size,
                              hipStream_t stream) {
  const float* x = (const float*)d_in[0];       // [4,2048,1024]
  const float* w_qkv = (const float*)d_in[1];   // [1024,3072]
  const float* w_o = (const float*)d_in[2];     // [1024,1024]
  float* out = (float*)d_out;                   // [4,2048,1024]
  short* ws = (short*)d_ws;
  short* xb = ws;                       // bf16 x; later reused as concat
  short* wqkvT = xb + 8388608;          // [3072][1024]
  short* woT = wqkvT + 3145728;         // [1024][1024]
  short* q = woT + 1048576;             // [B,H,T,dh], pre-scaled 1/32
  short* kb = q + 8388608;              // [B,H,T,dh]
  short* vt = kb + 8388608;             // [B,H,dh,T]

  cvt_f32_bf16<<<8192, 256, 0, stream>>>(x, xb, 2097152);
  transpose_cvt<<<dim3(96, 32), 256, 0, stream>>>(w_qkv, wqkvT, 1024, 3072);
  transpose_cvt<<<dim3(32, 32), 256, 0, stream>>>(w_o, woT, 1024, 1024);
  gemm_qkv<<<dim3(32, 24), 512, 0, stream>>>(xb, wqkvT, q, kb, vt);
  attn<<<dim3(2048), 256, 0, stream>>>(q, kb, vt, xb /*concat reuses xb*/);
  gemm_out<<<dim3(64, 8), 256, 0, stream>>>(xb, woT, out);
}